// Round 1
// baseline (225.589 us; speedup 1.0000x reference)
//
#include <hip/hip_runtime.h>
#include <hip/hip_fp16.h>

// MultiHeadAttention_64106681860559 — round 1: correctness-first fp16-MFMA pipeline.
// x(4096x1024) @ w_qkv(1024x3072) + b -> qkv; S = q@k^T * 0.125 (full 1024-dim);
// P = softmax(S); attn = P@v; out = attn@w_out + b_out.
//
// Workspace layout (needs ~142 MB):
//   xb    fp16 [4096][1024]   @ 0      (8 MB)   -- reused as attn after gemm1
//   wqkvT fp16 [3072][1024]   @ 8 MB   (6 MB)   -- reused as woutT after gemm1
//   qkv   fp16 [4096][3072]   @ 14 MB  (24 MB)
//   vT    fp16 [1024][4096]   @ 38 MB  (8 MB)
//   S     f32  [4096][4096]   @ 46 MB  (64 MB)
//   P     fp16 [4096][4096]   @ 110 MB (32 MB)

typedef _Float16 half_t;
typedef _Float16 half8 __attribute__((ext_vector_type(8)));
typedef _Float16 half4 __attribute__((ext_vector_type(4)));
typedef float f32x4 __attribute__((ext_vector_type(4)));

static constexpr int N_TOK = 4096;
static constexpr int LATENT = 1024;
static constexpr int QKVN = 3072;

#define DEVI __device__ __forceinline__

DEVI void gld_lds16(const half_t* g, half_t* l) {
  __builtin_amdgcn_global_load_lds(
      (const __attribute__((address_space(1))) void*)g,
      (__attribute__((address_space(3))) void*)l,
      16, 0, 0);
}

// ---------------------------------------------------------------------------
// GEMM: C[M][N] = A[M][K] @ B^T  where B is stored [N][K] (K contiguous).
// 128x128 block tile, 4 waves (2x2 of 64x64 each), BK=32, mfma_f32_16x16x32_f16.
// MODE 0: +bias, cols<1024 scaled by 0.125, fp16 out (qkv)
// MODE 1: f32 out (scores)
// MODE 2: fp16 out (attn)
// MODE 3: +bias, f32 out (final)
// ---------------------------------------------------------------------------
template <int MODE>
__launch_bounds__(256, 2)
__global__ void gemm_mfma(const half_t* __restrict__ A, int lda,
                          const half_t* __restrict__ B, int ldb,
                          void* __restrict__ Cout, int ldc,
                          const float* __restrict__ bias, int K) {
  __shared__ half_t At[128 * 32];
  __shared__ half_t Bt[128 * 32];

  const int tid = threadIdx.x;
  const int lane = tid & 63;
  const int wid = tid >> 6;
  const int rowBlk = blockIdx.y * 128;
  const int colBlk = blockIdx.x * 128;

  const int wr = (wid >> 1) * 64;   // wave row offset in tile
  const int wc = (wid & 1) * 64;    // wave col offset in tile
  const int fr = lane & 15;         // fragment row/col
  const int fk = (lane >> 4) * 8;   // fragment k offset

  f32x4 acc[4][4] = {};

  for (int kk = 0; kk < K; kk += 32) {
    // Stage A/B tiles: 128 rows x 32 fp16 = 8 KB each = 512 x 16B chunks.
    // chunk c = i*256 + tid; LDS dest linear at c*16B (wave-uniform base + lane*16).
#pragma unroll
    for (int i = 0; i < 2; ++i) {
      int c = i * 256 + tid;
      int r = c >> 2;
      int k8 = (c & 3) * 8;
      gld_lds16(A + (size_t)(rowBlk + r) * lda + kk + k8, At + c * 8);
      gld_lds16(B + (size_t)(colBlk + r) * ldb + kk + k8, Bt + c * 8);
    }
    __syncthreads();

    half8 af[4], bf[4];
#pragma unroll
    for (int m = 0; m < 4; ++m)
      af[m] = *(const half8*)(At + (wr + m * 16 + fr) * 32 + fk);
#pragma unroll
    for (int n = 0; n < 4; ++n)
      bf[n] = *(const half8*)(Bt + (wc + n * 16 + fr) * 32 + fk);

#pragma unroll
    for (int m = 0; m < 4; ++m)
#pragma unroll
      for (int n = 0; n < 4; ++n)
        acc[m][n] = __builtin_amdgcn_mfma_f32_16x16x32_f16(af[m], bf[n], acc[m][n], 0, 0, 0);

    __syncthreads();
  }

  // Epilogue. C/D mapping (HW-verified): col = lane&15, row = (lane>>4)*4 + j.
#pragma unroll
  for (int m = 0; m < 4; ++m) {
#pragma unroll
    for (int n = 0; n < 4; ++n) {
#pragma unroll
      for (int j = 0; j < 4; ++j) {
        int row = rowBlk + wr + m * 16 + (lane >> 4) * 4 + j;
        int col = colBlk + wc + n * 16 + fr;
        float v = acc[m][n][j];
        if (MODE == 0) {
          v += bias[col];
          if (col < 1024) v *= 0.125f;  // fold scores scale 1/sqrt(64) into q
          ((half_t*)Cout)[(size_t)row * ldc + col] = (half_t)v;
        } else if (MODE == 1) {
          ((float*)Cout)[(size_t)row * ldc + col] = v;
        } else if (MODE == 2) {
          ((half_t*)Cout)[(size_t)row * ldc + col] = (half_t)v;
        } else {
          ((float*)Cout)[(size_t)row * ldc + col] = v + bias[col];
        }
      }
    }
  }
}

// ---------------------------------------------------------------------------
// Row softmax: S f32 [4096][4096] -> P fp16. One block (256 thr) per row.
// ---------------------------------------------------------------------------
__launch_bounds__(256)
__global__ void softmax_rows(const float* __restrict__ S, half_t* __restrict__ P) {
  const int row = blockIdx.x;
  const int t = threadIdx.x;
  const float4* s4 = (const float4*)(S + (size_t)row * N_TOK);

  float4 v[4];
  float lmax = -1e30f;
#pragma unroll
  for (int i = 0; i < 4; ++i) {
    v[i] = s4[t + i * 256];
    lmax = fmaxf(lmax, fmaxf(fmaxf(v[i].x, v[i].y), fmaxf(v[i].z, v[i].w)));
  }
#pragma unroll
  for (int off = 32; off; off >>= 1) lmax = fmaxf(lmax, __shfl_xor(lmax, off));

  __shared__ float redm[4];
  __shared__ float reds[4];
  if ((t & 63) == 0) redm[t >> 6] = lmax;
  __syncthreads();
  lmax = fmaxf(fmaxf(redm[0], redm[1]), fmaxf(redm[2], redm[3]));

  float e[16];
  float lsum = 0.f;
#pragma unroll
  for (int i = 0; i < 4; ++i) {
    e[i * 4 + 0] = __expf(v[i].x - lmax);
    e[i * 4 + 1] = __expf(v[i].y - lmax);
    e[i * 4 + 2] = __expf(v[i].z - lmax);
    e[i * 4 + 3] = __expf(v[i].w - lmax);
    lsum += e[i * 4 + 0] + e[i * 4 + 1] + e[i * 4 + 2] + e[i * 4 + 3];
  }
#pragma unroll
  for (int off = 32; off; off >>= 1) lsum += __shfl_xor(lsum, off);
  if ((t & 63) == 0) reds[t >> 6] = lsum;
  __syncthreads();
  float inv = 1.f / (reds[0] + reds[1] + reds[2] + reds[3]);

  half4* p4 = (half4*)(P + (size_t)row * N_TOK);
#pragma unroll
  for (int i = 0; i < 4; ++i) {
    half4 h;
    h[0] = (half_t)(e[i * 4 + 0] * inv);
    h[1] = (half_t)(e[i * 4 + 1] * inv);
    h[2] = (half_t)(e[i * 4 + 2] * inv);
    h[3] = (half_t)(e[i * 4 + 3] * inv);
    p4[t + i * 256] = h;
  }
}

// ---------------------------------------------------------------------------
// Transpose [R][C] (row stride ldin) -> fp16 [C][R] (row stride ldout).
// Block (32,8), 32x32 tiles.
// ---------------------------------------------------------------------------
template <typename TI>
__global__ void transpose_to_f16(const TI* __restrict__ in, int ldin,
                                 half_t* __restrict__ out, int ldout) {
  __shared__ float tile[32][33];
  const int cb = blockIdx.x * 32;
  const int rb = blockIdx.y * 32;
  const int tx = threadIdx.x;
#pragma unroll
  for (int i = threadIdx.y; i < 32; i += 8)
    tile[i][tx] = (float)in[(size_t)(rb + i) * ldin + cb + tx];
  __syncthreads();
#pragma unroll
  for (int i = threadIdx.y; i < 32; i += 8)
    out[(size_t)(cb + i) * ldout + rb + tx] = (half_t)tile[tx][i];
}

__global__ void cvt_f32_f16(const float* __restrict__ in, half_t* __restrict__ out) {
  int i = blockIdx.x * 256 + threadIdx.x;  // one float4 per thread
  float4 v = ((const float4*)in)[i];
  half4 h;
  h[0] = (half_t)v.x; h[1] = (half_t)v.y; h[2] = (half_t)v.z; h[3] = (half_t)v.w;
  ((half4*)out)[i] = h;
}

extern "C" void kernel_launch(void* const* d_in, const int* in_sizes, int n_in,
                              void* d_out, int out_size, void* d_ws, size_t ws_size,
                              hipStream_t stream) {
  const float* x = (const float*)d_in[0];
  const float* w_qkv = (const float*)d_in[1];
  const float* b_qkv = (const float*)d_in[2];
  const float* w_out = (const float*)d_in[3];
  const float* b_out = (const float*)d_in[4];
  float* out = (float*)d_out;

  char* ws = (char*)d_ws;
  half_t* xb    = (half_t*)(ws);
  half_t* wqkvT = (half_t*)(ws + ((size_t)8 << 20));
  half_t* qkv   = (half_t*)(ws + ((size_t)14 << 20));
  half_t* vT    = (half_t*)(ws + ((size_t)38 << 20));
  float*  S     = (float*)(ws + ((size_t)46 << 20));
  half_t* P     = (half_t*)(ws + ((size_t)110 << 20));
  half_t* attn  = xb;     // xb dead after gemm<0>
  half_t* woutT = wqkvT;  // wqkvT dead after gemm<0>

  dim3 tb(32, 8);

  // 1. x -> fp16
  cvt_f32_f16<<<(N_TOK * LATENT) / (256 * 4), 256, 0, stream>>>(x, xb);
  // 2. w_qkv [1024][3072] -> wqkvT [3072][1024] fp16
  transpose_to_f16<float><<<dim3(QKVN / 32, LATENT / 32), tb, 0, stream>>>(w_qkv, QKVN, wqkvT, LATENT);
  // 3. qkv = x @ w_qkv + b  (q scaled by 0.125), fp16 [4096][3072]
  gemm_mfma<0><<<dim3(QKVN / 128, N_TOK / 128), 256, 0, stream>>>(
      xb, LATENT, wqkvT, LATENT, qkv, QKVN, b_qkv, LATENT);
  // 4. v (cols 2048..3071 of qkv) -> vT [1024][4096]
  transpose_to_f16<half_t><<<dim3(LATENT / 32, N_TOK / 32), tb, 0, stream>>>(
      qkv + 2 * LATENT, QKVN, vT, N_TOK);
  // 5. S = q' @ k^T   (f32 [4096][4096])
  gemm_mfma<1><<<dim3(N_TOK / 128, N_TOK / 128), 256, 0, stream>>>(
      qkv, QKVN, qkv + LATENT, QKVN, S, N_TOK, nullptr, LATENT);
  // 6. P = softmax rows (fp16)
  softmax_rows<<<N_TOK, 256, 0, stream>>>(S, P);
  // 7. attn = P @ v   (fp16 [4096][1024])
  gemm_mfma<2><<<dim3(LATENT / 128, N_TOK / 128), 256, 0, stream>>>(
      P, N_TOK, vT, N_TOK, attn, LATENT, nullptr, N_TOK);
  // 8. w_out [1024][1024] -> woutT fp16
  transpose_to_f16<float><<<dim3(LATENT / 32, LATENT / 32), tb, 0, stream>>>(w_out, LATENT, woutT, LATENT);
  // 9. out = attn @ w_out + b_out  (f32)
  gemm_mfma<3><<<dim3(LATENT / 128, N_TOK / 128), 256, 0, stream>>>(
      attn, LATENT, woutT, LATENT, out, LATENT, b_out, LATENT);
}

// Round 3
// 210.667 us; speedup vs baseline: 1.0708x; 1.0708x over previous
//
#include <hip/hip_runtime.h>
#include <hip/hip_fp16.h>

// MultiHeadAttention_64106681860559 — round 2 (resubmit after infra failure):
//  - 128x64 tiles for the skinny (N=1024) GEMMs: grid 256 -> 512 blocks (occupancy fix)
//  - LDS XOR swizzle (slot ^= (row>>1)&3) with pre-swizzled global_load_lds source
//    (rule 21: linear dest + inverse-swizzled source + swizzled read) -> kills the
//    8-way bank conflict on 64B-stride fragment reads
//  - XCD-aware bijective block swizzle for L2 panel reuse
//
// Workspace layout (~142 MB):
//   xb    fp16 [4096][1024]   @ 0      (8 MB)   -- reused as attn after gemm<0>
//   wqkvT fp16 [3072][1024]   @ 8 MB   (6 MB)   -- reused as woutT after gemm<0>
//   qkv   fp16 [4096][3072]   @ 14 MB  (24 MB)
//   vT    fp16 [1024][4096]   @ 38 MB  (8 MB)
//   S     f32  [4096][4096]   @ 46 MB  (64 MB)
//   P     fp16 [4096][4096]   @ 110 MB (32 MB)

typedef _Float16 half_t;
typedef _Float16 half8 __attribute__((ext_vector_type(8)));
typedef _Float16 half4 __attribute__((ext_vector_type(4)));
typedef float f32x4 __attribute__((ext_vector_type(4)));

static constexpr int N_TOK = 4096;
static constexpr int LATENT = 1024;
static constexpr int QKVN = 3072;

#define DEVI __device__ __forceinline__

DEVI void gld_lds16(const half_t* g, half_t* l) {
  __builtin_amdgcn_global_load_lds(
      (const __attribute__((address_space(1))) void*)g,
      (__attribute__((address_space(3))) void*)l,
      16, 0, 0);
}

// Swizzle: within a 64B LDS row (4 slots of 16B), logical slot s lives at
// physical slot s ^ ((row>>1)&3). Spreads 16-row fragment reads over all 8
// bank-quads (2-way residual = free per m136).
DEVI int slot_xor(int row) { return (row >> 1) & 3; }

// ---------------------------------------------------------------------------
// GEMM: C[M][N] = A[M][K] @ B^T  where B is stored [N][K] (K contiguous).
// BMxBN block tile, 4 waves as 2x2 of (BM/2)x(BN/2), BK=32, mfma 16x16x32 f16.
// MODE 0: +bias, cols<1024 scaled by 0.125, fp16 out (qkv)
// MODE 1: f32 out (scores)
// MODE 2: fp16 out (attn)
// MODE 3: +bias, f32 out (final)
// ---------------------------------------------------------------------------
template <int BM, int BN, int MODE>
__launch_bounds__(256, 2)
__global__ void gemm_mfma(const half_t* __restrict__ A, int lda,
                          const half_t* __restrict__ B, int ldb,
                          void* __restrict__ Cout, int ldc,
                          const float* __restrict__ bias, int K) {
  constexpr int MF = BM / 32;  // m-fragments per wave
  constexpr int NF = BN / 32;  // n-fragments per wave
  __shared__ half_t At[BM * 32];
  __shared__ half_t Bt[BN * 32];

  const int tid = threadIdx.x;
  const int lane = tid & 63;
  const int wid = tid >> 6;

  // XCD-aware bijective remap (all grids used are multiples of 8).
  const int nx = gridDim.x;
  const int nwg = nx * gridDim.y;
  const int bid = blockIdx.y * nx + blockIdx.x;
  const int cpx = nwg >> 3;
  const int swz = (bid & 7) * cpx + (bid >> 3);
  const int rowBlk = (swz / nx) * BM;
  const int colBlk = (swz % nx) * BN;

  const int wr = (wid >> 1) * (BM / 2);
  const int wc = (wid & 1) * (BN / 2);
  const int fr = lane & 15;
  const int fs = lane >> 4;  // logical 16B slot (k-offset fs*8)

  f32x4 acc[MF][NF] = {};

  for (int kk = 0; kk < K; kk += 32) {
    // Stage tiles. Physical chunk c=(row r, phys slot p) holds logical slot
    // p ^ slot_xor(r) -> pre-swizzle the global k-offset; LDS dest is linear.
#pragma unroll
    for (int c = tid; c < BM * 4; c += 256) {
      int r = c >> 2;
      int k8 = ((c & 3) ^ slot_xor(r)) * 8;
      gld_lds16(A + (size_t)(rowBlk + r) * lda + kk + k8, At + c * 8);
    }
#pragma unroll
    for (int c = tid; c < BN * 4; c += 256) {
      int r = c >> 2;
      int k8 = ((c & 3) ^ slot_xor(r)) * 8;
      gld_lds16(B + (size_t)(colBlk + r) * ldb + kk + k8, Bt + c * 8);
    }
    __syncthreads();

    half8 af[MF], bf[NF];
#pragma unroll
    for (int m = 0; m < MF; ++m) {
      int row = wr + m * 16 + fr;
      af[m] = *(const half8*)(At + row * 32 + (fs ^ slot_xor(row)) * 8);
    }
#pragma unroll
    for (int n = 0; n < NF; ++n) {
      int row = wc + n * 16 + fr;
      bf[n] = *(const half8*)(Bt + row * 32 + (fs ^ slot_xor(row)) * 8);
    }

#pragma unroll
    for (int m = 0; m < MF; ++m)
#pragma unroll
      for (int n = 0; n < NF; ++n)
        acc[m][n] = __builtin_amdgcn_mfma_f32_16x16x32_f16(af[m], bf[n], acc[m][n], 0, 0, 0);

    __syncthreads();
  }

  // Epilogue. C/D mapping: col = lane&15, row = (lane>>4)*4 + j.
#pragma unroll
  for (int m = 0; m < MF; ++m) {
#pragma unroll
    for (int n = 0; n < NF; ++n) {
#pragma unroll
      for (int j = 0; j < 4; ++j) {
        int row = rowBlk + wr + m * 16 + (lane >> 4) * 4 + j;
        int col = colBlk + wc + n * 16 + fr;
        float v = acc[m][n][j];
        if (MODE == 0) {
          v += bias[col];
          if (col < 1024) v *= 0.125f;  // fold 1/sqrt(DK) into q
          ((half_t*)Cout)[(size_t)row * ldc + col] = (half_t)v;
        } else if (MODE == 1) {
          ((float*)Cout)[(size_t)row * ldc + col] = v;
        } else if (MODE == 2) {
          ((half_t*)Cout)[(size_t)row * ldc + col] = (half_t)v;
        } else {
          ((float*)Cout)[(size_t)row * ldc + col] = v + bias[col];
        }
      }
    }
  }
}

// ---------------------------------------------------------------------------
// Row softmax: S f32 [4096][4096] -> P fp16. One block (256 thr) per row.
// ---------------------------------------------------------------------------
__launch_bounds__(256)
__global__ void softmax_rows(const float* __restrict__ S, half_t* __restrict__ P) {
  const int row = blockIdx.x;
  const int t = threadIdx.x;
  const float4* s4 = (const float4*)(S + (size_t)row * N_TOK);

  float4 v[4];
  float lmax = -1e30f;
#pragma unroll
  for (int i = 0; i < 4; ++i) {
    v[i] = s4[t + i * 256];
    lmax = fmaxf(lmax, fmaxf(fmaxf(v[i].x, v[i].y), fmaxf(v[i].z, v[i].w)));
  }
#pragma unroll
  for (int off = 32; off; off >>= 1) lmax = fmaxf(lmax, __shfl_xor(lmax, off));

  __shared__ float redm[4];
  __shared__ float reds[4];
  if ((t & 63) == 0) redm[t >> 6] = lmax;
  __syncthreads();
  lmax = fmaxf(fmaxf(redm[0], redm[1]), fmaxf(redm[2], redm[3]));

  float e[16];
  float lsum = 0.f;
#pragma unroll
  for (int i = 0; i < 4; ++i) {
    e[i * 4 + 0] = __expf(v[i].x - lmax);
    e[i * 4 + 1] = __expf(v[i].y - lmax);
    e[i * 4 + 2] = __expf(v[i].z - lmax);
    e[i * 4 + 3] = __expf(v[i].w - lmax);
    lsum += e[i * 4 + 0] + e[i * 4 + 1] + e[i * 4 + 2] + e[i * 4 + 3];
  }
#pragma unroll
  for (int off = 32; off; off >>= 1) lsum += __shfl_xor(lsum, off);
  if ((t & 63) == 0) reds[t >> 6] = lsum;
  __syncthreads();
  float inv = 1.f / (reds[0] + reds[1] + reds[2] + reds[3]);

  half4* p4 = (half4*)(P + (size_t)row * N_TOK);
#pragma unroll
  for (int i = 0; i < 4; ++i) {
    half4 h;
    h[0] = (half_t)(e[i * 4 + 0] * inv);
    h[1] = (half_t)(e[i * 4 + 1] * inv);
    h[2] = (half_t)(e[i * 4 + 2] * inv);
    h[3] = (half_t)(e[i * 4 + 3] * inv);
    p4[t + i * 256] = h;
  }
}

// ---------------------------------------------------------------------------
// Transpose [R][C] (row stride ldin) -> fp16 [C][R] (row stride ldout).
// ---------------------------------------------------------------------------
template <typename TI>
__global__ void transpose_to_f16(const TI* __restrict__ in, int ldin,
                                 half_t* __restrict__ out, int ldout) {
  __shared__ float tile[32][33];
  const int cb = blockIdx.x * 32;
  const int rb = blockIdx.y * 32;
  const int tx = threadIdx.x;
#pragma unroll
  for (int i = threadIdx.y; i < 32; i += 8)
    tile[i][tx] = (float)in[(size_t)(rb + i) * ldin + cb + tx];
  __syncthreads();
#pragma unroll
  for (int i = threadIdx.y; i < 32; i += 8)
    out[(size_t)(cb + i) * ldout + rb + tx] = (half_t)tile[tx][i];
}

__global__ void cvt_f32_f16(const float* __restrict__ in, half_t* __restrict__ out) {
  int i = blockIdx.x * 256 + threadIdx.x;  // one float4 per thread
  float4 v = ((const float4*)in)[i];
  half4 h;
  h[0] = (half_t)v.x; h[1] = (half_t)v.y; h[2] = (half_t)v.z; h[3] = (half_t)v.w;
  ((half4*)out)[i] = h;
}

extern "C" void kernel_launch(void* const* d_in, const int* in_sizes, int n_in,
                              void* d_out, int out_size, void* d_ws, size_t ws_size,
                              hipStream_t stream) {
  const float* x = (const float*)d_in[0];
  const float* w_qkv = (const float*)d_in[1];
  const float* b_qkv = (const float*)d_in[2];
  const float* w_out = (const float*)d_in[3];
  const float* b_out = (const float*)d_in[4];
  float* out = (float*)d_out;

  char* ws = (char*)d_ws;
  half_t* xb    = (half_t*)(ws);
  half_t* wqkvT = (half_t*)(ws + ((size_t)8 << 20));
  half_t* qkv   = (half_t*)(ws + ((size_t)14 << 20));
  half_t* vT    = (half_t*)(ws + ((size_t)38 << 20));
  float*  S     = (float*)(ws + ((size_t)46 << 20));
  half_t* P     = (half_t*)(ws + ((size_t)110 << 20));
  half_t* attn  = xb;     // xb dead after gemm<0>
  half_t* woutT = wqkvT;  // wqkvT dead after gemm<0>

  dim3 tb(32, 8);

  // 1. x -> fp16
  cvt_f32_f16<<<(N_TOK * LATENT) / (256 * 4), 256, 0, stream>>>(x, xb);
  // 2. w_qkv [1024][3072] -> wqkvT [3072][1024] fp16
  transpose_to_f16<float><<<dim3(QKVN / 32, LATENT / 32), tb, 0, stream>>>(w_qkv, QKVN, wqkvT, LATENT);
  // 3. qkv = x @ w_qkv + b  (q scaled by 0.125), fp16 [4096][3072]  (768 blocks)
  gemm_mfma<128, 128, 0><<<dim3(QKVN / 128, N_TOK / 128), 256, 0, stream>>>(
      xb, LATENT, wqkvT, LATENT, qkv, QKVN, b_qkv, LATENT);
  // 4. v (cols 2048..3071 of qkv) -> vT [1024][4096]
  transpose_to_f16<half_t><<<dim3(LATENT / 32, N_TOK / 32), tb, 0, stream>>>(
      qkv + 2 * LATENT, QKVN, vT, N_TOK);
  // 5. S = q' @ k^T   (f32 [4096][4096])  (1024 blocks)
  gemm_mfma<128, 128, 1><<<dim3(N_TOK / 128, N_TOK / 128), 256, 0, stream>>>(
      qkv, QKVN, qkv + LATENT, QKVN, S, N_TOK, nullptr, LATENT);
  // 6. P = softmax rows (fp16)
  softmax_rows<<<N_TOK, 256, 0, stream>>>(S, P);
  // 7. attn = P @ v   (fp16 [4096][1024])  (512 blocks @ 128x64)
  gemm_mfma<128, 64, 2><<<dim3(LATENT / 64, N_TOK / 128), 256, 0, stream>>>(
      P, N_TOK, vT, N_TOK, attn, LATENT, nullptr, N_TOK);
  // 8. w_out [1024][1024] -> woutT fp16
  transpose_to_f16<float><<<dim3(LATENT / 32, LATENT / 32), tb, 0, stream>>>(w_out, LATENT, woutT, LATENT);
  // 9. out = attn @ w_out + b_out  (f32)  (512 blocks @ 128x64)
  gemm_mfma<128, 64, 3><<<dim3(LATENT / 64, N_TOK / 128), 256, 0, stream>>>(
      attn, LATENT, woutT, LATENT, out, LATENT, b_out, LATENT);
}

// Round 6
// 204.970 us; speedup vs baseline: 1.1006x; 1.0278x over previous
//
#include <hip/hip_runtime.h>
#include <hip/hip_fp16.h>

// MultiHeadAttention_64106681860559 — round 4 (resubmit; infra failure x3):
//  - T3-minimum 2-phase: double-buffered LDS, prefetch issued BEFORE compute,
//    ONE barrier per K-tile (vmcnt(0) drain overlaps the MFMA phase)
//  - BK=64 (2x MFMA per barrier, half the iterations)
//  - gemm<2> (P@V) back to 128x128 (MFMA density)
//  - S stored fp16 (halves scores-write + softmax-read traffic)
//  - LDS swizzle for 128B rows: phys_slot = logical_slot ^ (row&7), applied on
//    pre-swizzled global_load_lds SOURCE + swizzled ds_read (rule 21)
//
// Workspace (~142 MB): xb fp16 4096x1024 @0 (reused as attn) | wqkvT fp16
// 3072x1024 @8M (reused as woutT) | qkv fp16 4096x3072 @14M | vT fp16
// 1024x4096 @38M | S fp16 4096x4096 @46M | P fp16 4096x4096 @110M

typedef _Float16 half_t;
typedef _Float16 half8 __attribute__((ext_vector_type(8)));
typedef _Float16 half4 __attribute__((ext_vector_type(4)));
typedef float f32x4 __attribute__((ext_vector_type(4)));

static constexpr int N_TOK = 4096;
static constexpr int LATENT = 1024;
static constexpr int QKVN = 3072;

#define DEVI __device__ __forceinline__

DEVI void gld_lds16(const half_t* g, half_t* l) {
  __builtin_amdgcn_global_load_lds(
      (const __attribute__((address_space(1))) void*)g,
      (__attribute__((address_space(3))) void*)l,
      16, 0, 0);
}

// Stage ROWS x 64 fp16 tile (row stride ld) into LDS at lbase, linear dest.
// Physical 16B slot p of row r holds logical slot p ^ (r&7) -> source k-offset
// pre-swizzled; fragment reads apply the same XOR.
template <int ROWS>
DEVI void stage64(const half_t* __restrict__ g, int ld, half_t* lbase, int tid) {
  constexpr int CH = ROWS * 8;  // 16B chunks
#pragma unroll
  for (int c = tid; c < CH; c += 256) {
    int r = c >> 3;
    int k8 = ((c & 7) ^ (r & 7)) * 8;
    gld_lds16(g + (size_t)r * ld + k8, lbase + c * 8);
  }
}

// ---------------------------------------------------------------------------
// GEMM: C[M][N] = A[M][K] @ B^T, B stored [N][K]. BMxBN tile, 4 waves as 2x2,
// BK=64, double-buffered LDS, one barrier per K-tile.
// MODE 0: +bias, cols<1024 scaled 0.125, fp16 out (qkv)
// MODE 1: fp16 out (scores)
// MODE 2: fp16 out (attn)
// MODE 3: +bias, f32 out (final)
// ---------------------------------------------------------------------------
template <int BM, int BN, int MODE>
__launch_bounds__(256, 2)
__global__ void gemm_mfma(const half_t* __restrict__ A, int lda,
                          const half_t* __restrict__ B, int ldb,
                          void* __restrict__ Cout, int ldc,
                          const float* __restrict__ bias, int K) {
  constexpr int MF = BM / 32;
  constexpr int NF = BN / 32;
  __shared__ half_t At[2][BM * 64];
  __shared__ half_t Bt[2][BN * 64];

  const int tid = threadIdx.x;
  const int lane = tid & 63;
  const int wid = tid >> 6;

  // XCD-aware bijective remap (all grids are multiples of 8).
  const int nx = gridDim.x;
  const int nwg = nx * gridDim.y;
  const int bid = blockIdx.y * nx + blockIdx.x;
  const int cpx = nwg >> 3;
  const int swz = (bid & 7) * cpx + (bid >> 3);
  const int rowBlk = (swz / nx) * BM;
  const int colBlk = (swz % nx) * BN;

  const int wr = (wid >> 1) * (BM / 2);
  const int wc = (wid & 1) * (BN / 2);
  const int fr = lane & 15;
  const int fs = lane >> 4;  // 0..3: k-offset fs*8 within a 32-wide k-half

  const half_t* Ag = A + (size_t)rowBlk * lda;
  const half_t* Bg = B + (size_t)colBlk * ldb;

  f32x4 acc[MF][NF] = {};

  const int NT = K >> 6;
  stage64<BM>(Ag, lda, At[0], tid);
  stage64<BN>(Bg, ldb, Bt[0], tid);
  __syncthreads();

  int cur = 0;
  for (int t = 0; t < NT; ++t) {
    if (t + 1 < NT) {
      stage64<BM>(Ag + (t + 1) * 64, lda, At[cur ^ 1], tid);
      stage64<BN>(Bg + (t + 1) * 64, ldb, Bt[cur ^ 1], tid);
    }
    const half_t* Ac = At[cur];
    const half_t* Bc = Bt[cur];
#pragma unroll
    for (int kh = 0; kh < 2; ++kh) {
      half8 af[MF], bf[NF];
#pragma unroll
      for (int m = 0; m < MF; ++m) {
        int row = wr + m * 16 + fr;
        af[m] = *(const half8*)(Ac + row * 64 + (((kh * 4 + fs) ^ (row & 7)) * 8));
      }
#pragma unroll
      for (int n = 0; n < NF; ++n) {
        int row = wc + n * 16 + fr;
        bf[n] = *(const half8*)(Bc + row * 64 + (((kh * 4 + fs) ^ (row & 7)) * 8));
      }
#pragma unroll
      for (int m = 0; m < MF; ++m)
#pragma unroll
        for (int n = 0; n < NF; ++n)
          acc[m][n] = __builtin_amdgcn_mfma_f32_16x16x32_f16(af[m], bf[n], acc[m][n], 0, 0, 0);
    }
    __syncthreads();  // drains vmcnt (stage complete) + frees buf[cur] readers
    cur ^= 1;
  }

  // Epilogue. C/D mapping: col = lane&15, row = (lane>>4)*4 + j.
#pragma unroll
  for (int m = 0; m < MF; ++m) {
#pragma unroll
    for (int n = 0; n < NF; ++n) {
#pragma unroll
      for (int j = 0; j < 4; ++j) {
        int row = rowBlk + wr + m * 16 + (lane >> 4) * 4 + j;
        int col = colBlk + wc + n * 16 + fr;
        float v = acc[m][n][j];
        if (MODE == 0) {
          v += bias[col];
          if (col < 1024) v *= 0.125f;  // fold 1/sqrt(DK) into q
          ((half_t*)Cout)[(size_t)row * ldc + col] = (half_t)v;
        } else if (MODE == 1) {
          ((half_t*)Cout)[(size_t)row * ldc + col] = (half_t)v;
        } else if (MODE == 2) {
          ((half_t*)Cout)[(size_t)row * ldc + col] = (half_t)v;
        } else {
          ((float*)Cout)[(size_t)row * ldc + col] = v + bias[col];
        }
      }
    }
  }
}

// ---------------------------------------------------------------------------
// Row softmax: S fp16 [4096][4096] -> P fp16. One block (256 thr) per row.
// ---------------------------------------------------------------------------
__launch_bounds__(256)
__global__ void softmax_rows(const half_t* __restrict__ S, half_t* __restrict__ P) {
  const int row = blockIdx.x;
  const int t = threadIdx.x;
  const half8* s8 = (const half8*)(S + (size_t)row * N_TOK);

  half8 v[2];
  float lmax = -1e30f;
#pragma unroll
  for (int i = 0; i < 2; ++i) {
    v[i] = s8[t + i * 256];
#pragma unroll
    for (int j = 0; j < 8; ++j) lmax = fmaxf(lmax, (float)v[i][j]);
  }
#pragma unroll
  for (int off = 32; off; off >>= 1) lmax = fmaxf(lmax, __shfl_xor(lmax, off));

  __shared__ float redm[4];
  __shared__ float reds[4];
  if ((t & 63) == 0) redm[t >> 6] = lmax;
  __syncthreads();
  lmax = fmaxf(fmaxf(redm[0], redm[1]), fmaxf(redm[2], redm[3]));

  float e[16];
  float lsum = 0.f;
#pragma unroll
  for (int i = 0; i < 2; ++i)
#pragma unroll
    for (int j = 0; j < 8; ++j) {
      float ev = __expf((float)v[i][j] - lmax);
      e[i * 8 + j] = ev;
      lsum += ev;
    }
#pragma unroll
  for (int off = 32; off; off >>= 1) lsum += __shfl_xor(lsum, off);
  if ((t & 63) == 0) reds[t >> 6] = lsum;
  __syncthreads();
  float inv = 1.f / (reds[0] + reds[1] + reds[2] + reds[3]);

  half8* p8 = (half8*)(P + (size_t)row * N_TOK);
#pragma unroll
  for (int i = 0; i < 2; ++i) {
    half8 h;
#pragma unroll
    for (int j = 0; j < 8; ++j) h[j] = (half_t)(e[i * 8 + j] * inv);
    p8[t + i * 256] = h;
  }
}

// ---------------------------------------------------------------------------
// Transpose [R][C] (row stride ldin) -> fp16 [C][R] (row stride ldout).
// ---------------------------------------------------------------------------
template <typename TI>
__global__ void transpose_to_f16(const TI* __restrict__ in, int ldin,
                                 half_t* __restrict__ out, int ldout) {
  __shared__ float tile[32][33];
  const int cb = blockIdx.x * 32;
  const int rb = blockIdx.y * 32;
  const int tx = threadIdx.x;
#pragma unroll
  for (int i = threadIdx.y; i < 32; i += 8)
    tile[i][tx] = (float)in[(size_t)(rb + i) * ldin + cb + tx];
  __syncthreads();
#pragma unroll
  for (int i = threadIdx.y; i < 32; i += 8)
    out[(size_t)(cb + i) * ldout + rb + tx] = (half_t)tile[tx][i];
}

__global__ void cvt_f32_f16(const float* __restrict__ in, half_t* __restrict__ out) {
  int i = blockIdx.x * 256 + threadIdx.x;  // one float4 per thread
  float4 v = ((const float4*)in)[i];
  half4 h;
  h[0] = (half_t)v.x; h[1] = (half_t)v.y; h[2] = (half_t)v.z; h[3] = (half_t)v.w;
  ((half4*)out)[i] = h;
}

extern "C" void kernel_launch(void* const* d_in, const int* in_sizes, int n_in,
                              void* d_out, int out_size, void* d_ws, size_t ws_size,
                              hipStream_t stream) {
  const float* x = (const float*)d_in[0];
  const float* w_qkv = (const float*)d_in[1];
  const float* b_qkv = (const float*)d_in[2];
  const float* w_out = (const float*)d_in[3];
  const float* b_out = (const float*)d_in[4];
  float* out = (float*)d_out;

  char* ws = (char*)d_ws;
  half_t* xb    = (half_t*)(ws);
  half_t* wqkvT = (half_t*)(ws + ((size_t)8 << 20));
  half_t* qkv   = (half_t*)(ws + ((size_t)14 << 20));
  half_t* vT    = (half_t*)(ws + ((size_t)38 << 20));
  half_t* S     = (half_t*)(ws + ((size_t)46 << 20));
  half_t* P     = (half_t*)(ws + ((size_t)110 << 20));
  half_t* attn  = xb;     // xb dead after gemm<0>
  half_t* woutT = wqkvT;  // wqkvT dead after gemm<0>

  dim3 tb(32, 8);

  // 1. x -> fp16
  cvt_f32_f16<<<(N_TOK * LATENT) / (256 * 4), 256, 0, stream>>>(x, xb);
  // 2. w_qkv [1024][3072] -> wqkvT [3072][1024] fp16
  transpose_to_f16<float><<<dim3(QKVN / 32, LATENT / 32), tb, 0, stream>>>(w_qkv, QKVN, wqkvT, LATENT);
  // 3. qkv = x @ w_qkv + b (q scaled 0.125), fp16 [4096][3072]  (768 blocks)
  gemm_mfma<128, 128, 0><<<dim3(QKVN / 128, N_TOK / 128), 256, 0, stream>>>(
      xb, LATENT, wqkvT, LATENT, qkv, QKVN, b_qkv, LATENT);
  // 4. v (cols 2048..3071 of qkv) -> vT [1024][4096]
  transpose_to_f16<half_t><<<dim3(LATENT / 32, N_TOK / 32), tb, 0, stream>>>(
      qkv + 2 * LATENT, QKVN, vT, N_TOK);
  // 5. S = q' @ k^T, fp16  (1024 blocks)
  gemm_mfma<128, 128, 1><<<dim3(N_TOK / 128, N_TOK / 128), 256, 0, stream>>>(
      qkv, QKVN, qkv + LATENT, QKVN, S, N_TOK, nullptr, LATENT);
  // 6. P = softmax rows (fp16)
  softmax_rows<<<N_TOK, 256, 0, stream>>>(S, P);
  // 7. attn = P @ v, fp16  (256 blocks @ 128x128)
  gemm_mfma<128, 128, 2><<<dim3(LATENT / 128, N_TOK / 128), 256, 0, stream>>>(
      P, N_TOK, vT, N_TOK, attn, LATENT, nullptr, N_TOK);
  // 8. w_out [1024][1024] -> woutT fp16
  transpose_to_f16<float><<<dim3(LATENT / 32, LATENT / 32), tb, 0, stream>>>(w_out, LATENT, woutT, LATENT);
  // 9. out = attn @ w_out + b_out, f32  (512 blocks @ 128x64)
  gemm_mfma<128, 64, 3><<<dim3(LATENT / 64, N_TOK / 128), 256, 0, stream>>>(
      attn, LATENT, woutT, LATENT, out, LATENT, b_out, LATENT);
}

// Round 8
// 191.061 us; speedup vs baseline: 1.1807x; 1.0728x over previous
//
#include <hip/hip_runtime.h>
#include <hip/hip_fp16.h>

// MultiHeadAttention_64106681860559 — round 7 (resubmit; infra failure):
//  - Associativity fusion: out = P@(v@w_out)+b — gemm<3> and the attn buffer die.
//  - N=1024 GEMMs use 128x64 tiles (512 blocks, 2/CU) with the dbuf BK=64 loop.
//  - Everything else as R6 (0 bank conflicts, XCD swizzle, fp16 S).
//
// Workspace (~128 MB):
//   xb    fp16 [4096][1024] @ 0     (8 MB)
//   wqkvT fp16 [3072][1024] @ 8 MB  (6 MB)
//   qkv   fp16 [4096][3072] @ 14 MB (24 MB)
//   S     fp16 [4096][4096] @ 46 MB (32 MB)
//   P     fp16 [4096][4096] @ 78 MB (32 MB)
//   vw    fp16 [4096][1024] @ 110 MB (8 MB)
//   vwT   fp16 [1024][4096] @ 118 MB (8 MB)
//   woutT fp16 [1024][1024] @ 126 MB (2 MB)

typedef _Float16 half_t;
typedef _Float16 half8 __attribute__((ext_vector_type(8)));
typedef _Float16 half4 __attribute__((ext_vector_type(4)));
typedef float f32x4 __attribute__((ext_vector_type(4)));

static constexpr int N_TOK = 4096;
static constexpr int LATENT = 1024;
static constexpr int QKVN = 3072;

#define DEVI __device__ __forceinline__

DEVI void gld_lds16(const half_t* g, half_t* l) {
  __builtin_amdgcn_global_load_lds(
      (const __attribute__((address_space(1))) void*)g,
      (__attribute__((address_space(3))) void*)l,
      16, 0, 0);
}

// Stage ROWS x 64 fp16 tile (row stride ld) into LDS, linear dest.
// Physical 16B slot p of row r holds logical slot p ^ (r&7): source k-offset
// pre-swizzled; fragment reads apply the same XOR (rule 21).
template <int ROWS>
DEVI void stage64(const half_t* __restrict__ g, int ld, half_t* lbase, int tid) {
  constexpr int CH = ROWS * 8;  // 16B chunks
#pragma unroll
  for (int c = tid; c < CH; c += 256) {
    int r = c >> 3;
    int k8 = ((c & 7) ^ (r & 7)) * 8;
    gld_lds16(g + (size_t)r * ld + k8, lbase + c * 8);
  }
}

// ---------------------------------------------------------------------------
// GEMM: C[M][N] = A[M][K] @ B^T, B stored [N][K]. BMxBN tile, 4 waves as 2x2,
// BK=64, double-buffered LDS, one barrier per K-tile.
// MODE 0: +bias, cols<1024 scaled 0.125, fp16 out (qkv)
// MODE 1: fp16 out (scores / vw)
// MODE 2: +bias, f32 out (final)
// ---------------------------------------------------------------------------
template <int BM, int BN, int MODE>
__launch_bounds__(256, 2)
__global__ void gemm_mfma(const half_t* __restrict__ A, int lda,
                          const half_t* __restrict__ B, int ldb,
                          void* __restrict__ Cout, int ldc,
                          const float* __restrict__ bias, int K) {
  constexpr int MF = BM / 32;
  constexpr int NF = BN / 32;
  __shared__ half_t At[2][BM * 64];
  __shared__ half_t Bt[2][BN * 64];

  const int tid = threadIdx.x;
  const int lane = tid & 63;
  const int wid = tid >> 6;

  // XCD-aware bijective remap (all grids are multiples of 8).
  const int nx = gridDim.x;
  const int nwg = nx * gridDim.y;
  const int bid = blockIdx.y * nx + blockIdx.x;
  const int cpx = nwg >> 3;
  const int swz = (bid & 7) * cpx + (bid >> 3);
  const int rowBlk = (swz / nx) * BM;
  const int colBlk = (swz % nx) * BN;

  const int wr = (wid >> 1) * (BM / 2);
  const int wc = (wid & 1) * (BN / 2);
  const int fr = lane & 15;
  const int fs = lane >> 4;  // 0..3: k-offset fs*8 within a 32-wide k-half

  const half_t* Ag = A + (size_t)rowBlk * lda;
  const half_t* Bg = B + (size_t)colBlk * ldb;

  f32x4 acc[MF][NF] = {};

  const int NT = K >> 6;
  stage64<BM>(Ag, lda, At[0], tid);
  stage64<BN>(Bg, ldb, Bt[0], tid);
  __syncthreads();

  int cur = 0;
  for (int t = 0; t < NT; ++t) {
    if (t + 1 < NT) {
      stage64<BM>(Ag + (t + 1) * 64, lda, At[cur ^ 1], tid);
      stage64<BN>(Bg + (t + 1) * 64, ldb, Bt[cur ^ 1], tid);
    }
    const half_t* Ac = At[cur];
    const half_t* Bc = Bt[cur];
#pragma unroll
    for (int kh = 0; kh < 2; ++kh) {
      half8 af[MF], bf[NF];
#pragma unroll
      for (int m = 0; m < MF; ++m) {
        int row = wr + m * 16 + fr;
        af[m] = *(const half8*)(Ac + row * 64 + (((kh * 4 + fs) ^ (row & 7)) * 8));
      }
#pragma unroll
      for (int n = 0; n < NF; ++n) {
        int row = wc + n * 16 + fr;
        bf[n] = *(const half8*)(Bc + row * 64 + (((kh * 4 + fs) ^ (row & 7)) * 8));
      }
#pragma unroll
      for (int m = 0; m < MF; ++m)
#pragma unroll
        for (int n = 0; n < NF; ++n)
          acc[m][n] = __builtin_amdgcn_mfma_f32_16x16x32_f16(af[m], bf[n], acc[m][n], 0, 0, 0);
    }
    __syncthreads();  // drains vmcnt (stage complete) + frees buf[cur] readers
    cur ^= 1;
  }

  // Epilogue. C/D mapping: col = lane&15, row = (lane>>4)*4 + j.
#pragma unroll
  for (int m = 0; m < MF; ++m) {
#pragma unroll
    for (int n = 0; n < NF; ++n) {
#pragma unroll
      for (int j = 0; j < 4; ++j) {
        int row = rowBlk + wr + m * 16 + (lane >> 4) * 4 + j;
        int col = colBlk + wc + n * 16 + fr;
        float v = acc[m][n][j];
        if (MODE == 0) {
          v += bias[col];
          if (col < 1024) v *= 0.125f;  // fold 1/sqrt(DK) into q
          ((half_t*)Cout)[(size_t)row * ldc + col] = (half_t)v;
        } else if (MODE == 1) {
          ((half_t*)Cout)[(size_t)row * ldc + col] = (half_t)v;
        } else {
          ((float*)Cout)[(size_t)row * ldc + col] = v + bias[col];
        }
      }
    }
  }
}

// ---------------------------------------------------------------------------
// Row softmax: S fp16 [4096][4096] -> P fp16. One block (256 thr) per row.
// ---------------------------------------------------------------------------
__launch_bounds__(256)
__global__ void softmax_rows(const half_t* __restrict__ S, half_t* __restrict__ P) {
  const int row = blockIdx.x;
  const int t = threadIdx.x;
  const half8* s8 = (const half8*)(S + (size_t)row * N_TOK);

  half8 v[2];
  float lmax = -1e30f;
#pragma unroll
  for (int i = 0; i < 2; ++i) {
    v[i] = s8[t + i * 256];
#pragma unroll
    for (int j = 0; j < 8; ++j) lmax = fmaxf(lmax, (float)v[i][j]);
  }
#pragma unroll
  for (int off = 32; off; off >>= 1) lmax = fmaxf(lmax, __shfl_xor(lmax, off));

  __shared__ float redm[4];
  __shared__ float reds[4];
  if ((t & 63) == 0) redm[t >> 6] = lmax;
  __syncthreads();
  lmax = fmaxf(fmaxf(redm[0], redm[1]), fmaxf(redm[2], redm[3]));

  float e[16];
  float lsum = 0.f;
#pragma unroll
  for (int i = 0; i < 2; ++i)
#pragma unroll
    for (int j = 0; j < 8; ++j) {
      float ev = __expf((float)v[i][j] - lmax);
      e[i * 8 + j] = ev;
      lsum += ev;
    }
#pragma unroll
  for (int off = 32; off; off >>= 1) lsum += __shfl_xor(lsum, off);
  if ((t & 63) == 0) reds[t >> 6] = lsum;
  __syncthreads();
  float inv = 1.f / (reds[0] + reds[1] + reds[2] + reds[3]);

  half8* p8 = (half8*)(P + (size_t)row * N_TOK);
#pragma unroll
  for (int i = 0; i < 2; ++i) {
    half8 h;
#pragma unroll
    for (int j = 0; j < 8; ++j) h[j] = (half_t)(e[i * 8 + j] * inv);
    p8[t + i * 256] = h;
  }
}

// ---------------------------------------------------------------------------
// Transpose [R][C] (row stride ldin) -> fp16 [C][R] (row stride ldout).
// ---------------------------------------------------------------------------
template <typename TI>
__global__ void transpose_to_f16(const TI* __restrict__ in, int ldin,
                                 half_t* __restrict__ out, int ldout) {
  __shared__ float tile[32][33];
  const int cb = blockIdx.x * 32;
  const int rb = blockIdx.y * 32;
  const int tx = threadIdx.x;
#pragma unroll
  for (int i = threadIdx.y; i < 32; i += 8)
    tile[i][tx] = (float)in[(size_t)(rb + i) * ldin + cb + tx];
  __syncthreads();
#pragma unroll
  for (int i = threadIdx.y; i < 32; i += 8)
    out[(size_t)(cb + i) * ldout + rb + tx] = (half_t)tile[tx][i];
}

__global__ void cvt_f32_f16(const float* __restrict__ in, half_t* __restrict__ out) {
  int i = blockIdx.x * 256 + threadIdx.x;  // one float4 per thread
  float4 v = ((const float4*)in)[i];
  half4 h;
  h[0] = (half_t)v.x; h[1] = (half_t)v.y; h[2] = (half_t)v.z; h[3] = (half_t)v.w;
  ((half4*)out)[i] = h;
}

extern "C" void kernel_launch(void* const* d_in, const int* in_sizes, int n_in,
                              void* d_out, int out_size, void* d_ws, size_t ws_size,
                              hipStream_t stream) {
  const float* x = (const float*)d_in[0];
  const float* w_qkv = (const float*)d_in[1];
  const float* b_qkv = (const float*)d_in[2];
  const float* w_out = (const float*)d_in[3];
  const float* b_out = (const float*)d_in[4];
  float* out = (float*)d_out;

  char* ws = (char*)d_ws;
  half_t* xb    = (half_t*)(ws);
  half_t* wqkvT = (half_t*)(ws + ((size_t)8 << 20));
  half_t* qkv   = (half_t*)(ws + ((size_t)14 << 20));
  half_t* S     = (half_t*)(ws + ((size_t)46 << 20));
  half_t* P     = (half_t*)(ws + ((size_t)78 << 20));
  half_t* vw    = (half_t*)(ws + ((size_t)110 << 20));
  half_t* vwT   = (half_t*)(ws + ((size_t)118 << 20));
  half_t* woutT = (half_t*)(ws + ((size_t)126 << 20));

  dim3 tb(32, 8);

  // 1. x -> fp16
  cvt_f32_f16<<<(N_TOK * LATENT) / (256 * 4), 256, 0, stream>>>(x, xb);
  // 2. w_qkv [1024][3072] -> wqkvT [3072][1024] fp16
  transpose_to_f16<float><<<dim3(QKVN / 32, LATENT / 32), tb, 0, stream>>>(w_qkv, QKVN, wqkvT, LATENT);
  // 3. w_out [1024][1024] -> woutT fp16 (independent, scheduled early)
  transpose_to_f16<float><<<dim3(LATENT / 32, LATENT / 32), tb, 0, stream>>>(w_out, LATENT, woutT, LATENT);
  // 4. qkv = x @ w_qkv + b (q scaled 0.125), fp16 [4096][3072]  (768 blocks)
  gemm_mfma<128, 128, 0><<<dim3(QKVN / 128, N_TOK / 128), 256, 0, stream>>>(
      xb, LATENT, wqkvT, LATENT, qkv, QKVN, b_qkv, LATENT);
  // 5. vw = v @ w_out, fp16 [4096][1024]  (v = qkv cols 2048.., K-contiguous)
  gemm_mfma<128, 64, 1><<<dim3(LATENT / 64, N_TOK / 128), 256, 0, stream>>>(
      qkv + 2 * LATENT, QKVN, woutT, LATENT, vw, LATENT, nullptr, LATENT);
  // 6. vw -> vwT [1024][4096]
  transpose_to_f16<half_t><<<dim3(LATENT / 32, N_TOK / 32), tb, 0, stream>>>(
      vw, LATENT, vwT, N_TOK);
  // 7. S = q' @ k^T, fp16  (1024 blocks)
  gemm_mfma<128, 128, 1><<<dim3(N_TOK / 128, N_TOK / 128), 256, 0, stream>>>(
      qkv, QKVN, qkv + LATENT, QKVN, S, N_TOK, nullptr, LATENT);
  // 8. P = softmax rows (fp16)
  softmax_rows<<<N_TOK, 256, 0, stream>>>(S, P);
  // 9. out = P @ vw + b_out, f32  (512 blocks @ 128x64)
  gemm_mfma<128, 64, 2><<<dim3(LATENT / 64, N_TOK / 128), 256, 0, stream>>>(
      P, N_TOK, vwT, N_TOK, out, LATENT, b_out, N_TOK);
}